// Round 13
// baseline (149.672 us; speedup 1.0000x reference)
//
#include <hip/hip_runtime.h>
#include <hip/hip_bf16.h>

#define T_TOKENS 2048
#define D_EMBD 768
#define N_EXP 64
#define EW 256
#define TOPK 8
#define TW (N_EXP*EW)
#define PAD_SLOTS 20480   // 16384 + 64*63 rounded up to 64-tile granularity
#define SCHED_MAX 2560    // 8 * 320 worst-case positions, mult of 512
#define OUT_BASE (2048*768)

typedef __attribute__((ext_vector_type(8))) short bf16x8;
typedef __attribute__((ext_vector_type(4))) float f32x4;

__device__ inline unsigned short f2bu(float f) {
  union { __hip_bfloat16 b; unsigned short u; } cv; cv.b = __float2bfloat16(f); return cv.u;
}
__device__ inline unsigned int pk2(float a, float b) {
  return (unsigned int)f2bu(a) | ((unsigned int)f2bu(b) << 16);
}

// ---------------- init ----------------
__global__ void k_init(int* counts, int* cursor, float* psum, float* scal,
                       float* wgt_slot, int* tok_slot, int* sched_e) {
  int i = blockIdx.x*256 + threadIdx.x;   // 20480 threads
  if (i < N_EXP) { counts[i] = 0; cursor[i] = 0; psum[i] = 0.f; }
  if (i < 2) scal[i] = 0.f;
  if (i < PAD_SLOTS) { wgt_slot[i] = 0.f; tok_slot[i] = 0; }
  if (i < SCHED_MAX) sched_e[i] = -1;
}

// ---------------- router logits GEMM: lp[kc][t][e] partial sums ----------------
__global__ __launch_bounds__(256) void k_logits(const float* __restrict__ x,
                                                const float* __restrict__ rw,
                                                float* __restrict__ lp) {
  __shared__ float rw_s[8][256];
  int tid = threadIdx.x;
  int tg = blockIdx.x, eg = blockIdx.y, kc = blockIdx.z;
  #pragma unroll
  for (int idx = 0; idx < 8; idx++)
    rw_s[idx][tid] = rw[(size_t)(eg*8 + idx)*D_EMBD + kc*256 + tid];
  __syncthreads();
  int tok = tg*256 + tid;
  const float4* x4 = reinterpret_cast<const float4*>(x + (size_t)tok*D_EMBD + kc*256);
  float acc[8];
  #pragma unroll
  for (int e = 0; e < 8; e++) acc[e] = 0.f;
  #pragma unroll 4
  for (int k4 = 0; k4 < 64; k4++) {
    float4 xv = x4[k4];
    #pragma unroll
    for (int e = 0; e < 8; e++)
      acc[e] += xv.x*rw_s[e][k4*4+0] + xv.y*rw_s[e][k4*4+1]
              + xv.z*rw_s[e][k4*4+2] + xv.w*rw_s[e][k4*4+3];
  }
  float* dst = lp + (size_t)kc*T_TOKENS*N_EXP + (size_t)tok*N_EXP + eg*8;
  float4 o0 = {acc[0], acc[1], acc[2], acc[3]};
  float4 o1 = {acc[4], acc[5], acc[6], acc[7]};
  reinterpret_cast<float4*>(dst)[0] = o0;
  reinterpret_cast<float4*>(dst)[1] = o1;
}

// ---------------- router part 2: sigmoid, parallel-rank top-8, losses ----------------
__global__ __launch_bounds__(256) void k_router2(const float* __restrict__ lp,
                          int* __restrict__ sel_e, float* __restrict__ sel_w,
                          int* __restrict__ counts, float* __restrict__ psum,
                          float* __restrict__ scal) {
  __shared__ float psum_s[4][64];
  __shared__ int cnt_s[4][64];
  int tid = threadIdx.x, wv = tid >> 6, lane = tid & 63;
  float pacc = 0.f, zacc = 0.f;
  int cacc = 0;
  int tbase = blockIdx.x*8 + wv*2;
  #pragma unroll
  for (int it = 0; it < 2; it++) {
    int t = tbase + it;
    float logit = lp[(size_t)t*N_EXP + lane]
                + lp[(size_t)T_TOKENS*N_EXP + (size_t)t*N_EXP + lane]
                + lp[2*(size_t)T_TOKENS*N_EXP + (size_t)t*N_EXP + lane];
    float prob = 1.f/(1.f + expf(-logit));
    pacc += prob;
    float mx = logit;
    for (int s = 32; s; s >>= 1) mx = fmaxf(mx, __shfl_xor(mx, s, 64));
    float sse = expf(logit - mx);
    for (int s = 32; s; s >>= 1) sse += __shfl_xor(sse, s, 64);
    float lse = mx + logf(sse);
    zacc += lse*lse;
    int rank = 0;
    #pragma unroll
    for (int j = 0; j < 64; j++) {
      float pj = __shfl(prob, j, 64);
      rank += (pj > prob || (pj == prob && j < lane)) ? 1 : 0;
    }
    bool sel = rank < TOPK;
    float sp = sel ? prob : 0.f;
    for (int s = 32; s; s >>= 1) sp += __shfl_xor(sp, s, 64);
    if (sel) {
      sel_e[t*TOPK + rank] = lane;
      sel_w[t*TOPK + rank] = prob / (sp + 1e-20f);
      cacc++;
    }
  }
  psum_s[wv][lane] = pacc;
  cnt_s[wv][lane] = cacc;
  if (lane == 0) atomicAdd(&scal[0], zacc);
  __syncthreads();
  if (tid < 64) {
    float p = psum_s[0][tid] + psum_s[1][tid] + psum_s[2][tid] + psum_s[3][tid];
    int c = cnt_s[0][tid] + cnt_s[1][tid] + cnt_s[2][tid] + cnt_s[3][tid];
    atomicAdd(&psum[tid], p);
    atomicAdd(&counts[tid], c);
  }
}

// ---------------- schedule: 64-row tiles, XCD-grouped positions ----------------
__global__ void k_schedule(const int* __restrict__ counts, int* __restrict__ offsets,
                           int* __restrict__ sched_e, int* __restrict__ sched_r0) {
  int e = threadIdx.x;   // 64 threads, one wave
  int c = counts[e];
  int tiles = (c + 63) >> 6;
  int padded = tiles << 6;
  int ip = padded;
  for (int s = 1; s < 64; s <<= 1) { int v = __shfl_up(ip, s, 64); if (e >= s) ip += v; }
  int rowoff = ip - padded;
  offsets[e] = rowoff;
  int it = tiles;
  for (int s = 8; s < 64; s <<= 1) { int v = __shfl_up(it, s, 64); if (e >= s) it += v; }
  int rank = it - tiles;
  int xcd = e & 7;
  for (int i = 0; i < tiles; i++) {
    int p = xcd + 8*(rank + i);
    sched_e[p] = e;
    sched_r0[p] = rowoff + i*64;
  }
}

// ---------------- assign tokens to slots ----------------
__global__ void k_assign(const int* __restrict__ sel_e, const float* __restrict__ sel_w,
                         const int* __restrict__ offsets, int* __restrict__ cursor,
                         int* __restrict__ tok_slot, float* __restrict__ wgt_slot,
                         int* __restrict__ slot_tk) {
  int i = blockIdx.x*256 + threadIdx.x;   // 16384
  int e = sel_e[i];
  int pos = atomicAdd(&cursor[e], 1);
  int slot = offsets[e] + pos;
  tok_slot[slot] = i >> 3;
  wgt_slot[slot] = sel_w[i];
  slot_tk[i] = slot;
}

// ---------------- grouped GEMM, fused cvt staging, 2-step-ahead reg pipeline ----------------
// 64x128 tile, BK=64, double-buffered LDS + double register slots.
// Step t: issue loads k(t+2) -> slot[t%2]; compute buf[t%2]; write buf[(t+1)%2]
// from slot[(t+1)%2] (loads a full step old -> vmcnt wait ~free); barrier.
template<int MODE>
__global__ __launch_bounds__(256) void k_moe_gemm(
    const void* __restrict__ Asrc, const float* __restrict__ Bsrc,
    const int* __restrict__ sched_e, const int* __restrict__ sched_r0,
    const int* __restrict__ tok_slot, const float* __restrict__ wgt_slot,
    __hip_bfloat16* __restrict__ outp) {
  constexpr int NS   = (MODE == 1) ? 12 : 4;       // K-steps of 64 (even)
  constexpr int BSTR = (MODE == 1) ? TW : D_EMBD;  // native B row stride (fp32)
  __shared__ __hip_bfloat16 As[2][64*64];
  __shared__ __hip_bfloat16 Bs[2][128*64];
  int tid = threadIdx.x;
  int nch = blockIdx.y;
  int n4 = tid & 31, kpb = tid >> 5;     // B staging: col-quad, k-octet
  int mrow = tid >> 4, k4f = tid & 15;   // A staging (MODE1)
  int arl = tid >> 3, akc = tid & 7;     // A staging (MODE2)
  int a_off = ((akc ^ (arl & 7)) << 3);
  int wv = tid >> 6, lane = tid & 63;
  int wm = wv >> 1, wn = wv & 1;
  int l15 = lane & 15, l4 = lane >> 4;

  for (int p = blockIdx.x; p < SCHED_MAX; p += gridDim.x) {
    int e = sched_e[p];
    if (e < 0) continue;
    int r0 = sched_r0[p];

    int browb = (MODE == 1) ? 0 : e*EW;                    // B k-row base
    int bcolb = (MODE == 1) ? (e*EW + nch*128) : nch*128;  // B col base

    int tks[4];
    size_t a_base0 = 0, a_base1 = 0;
    if (MODE == 1) {
      #pragma unroll
      for (int i = 0; i < 4; i++) tks[i] = tok_slot[r0 + i*16 + mrow];
    } else {
      a_base0 = (size_t)(r0 + arl) * EW;
      a_base1 = (size_t)(r0 + arl + 32) * EW;
    }

    // register slots (named; all indexing compile-time)
    float av0[4][4], av1[4][4];
    uint4 au0[2], au1[2];
    float bv0_[8][4], bv1_[8][4];

    auto B_LD = [&](float (&bv)[8][4], int k0) {
      const float* rp = Bsrc + (size_t)(browb + k0 + kpb*8)*BSTR + bcolb + n4*4;
      #pragma unroll
      for (int r = 0; r < 8; r++)
        *reinterpret_cast<float4*>(&bv[r][0]) =
            *reinterpret_cast<const float4*>(rp + (size_t)r*BSTR);
    };
    auto B_WR = [&](int bsel, float (&bv)[8][4]) {
      char* bs = (char*)&Bs[bsel][0];
      #pragma unroll
      for (int c = 0; c < 4; c++) {
        int n = n4*4 + c;
        int ch = kpb ^ ((n & 7) ^ ((n >> 3) & 7));
        uint4 o = { pk2(bv[0][c], bv[1][c]), pk2(bv[2][c], bv[3][c]),
                    pk2(bv[4][c], bv[5][c]), pk2(bv[6][c], bv[7][c]) };
        *reinterpret_cast<uint4*>(bs + n*128 + ch*16) = o;
      }
    };
    auto A_LD1 = [&](float (&av)[4][4], int k0) {
      const float* xf = (const float*)Asrc;
      #pragma unroll
      for (int i = 0; i < 4; i++)
        *reinterpret_cast<float4*>(&av[i][0]) =
            *reinterpret_cast<const float4*>(xf + (size_t)tks[i]*D_EMBD + k0 + k4f*4);
    };
    auto A_WR1 = [&](int bsel, float (&av)[4][4]) {
      char* as_ = (char*)&As[bsel][0];
      #pragma unroll
      for (int i = 0; i < 4; i++) {
        int m = i*16 + mrow;
        int ch = (k4f >> 1) ^ (m & 7);
        uint2 val = { pk2(av[i][0], av[i][1]), pk2(av[i][2], av[i][3]) };
        *reinterpret_cast<uint2*>(as_ + m*128 + ch*16 + (k4f & 1)*8) = val;
      }
    };
    auto A_LD2 = [&](uint4 (&au)[2], int k0) {
      const __hip_bfloat16* hb = (const __hip_bfloat16*)Asrc;
      au[0] = *reinterpret_cast<const uint4*>(hb + a_base0 + k0 + a_off);
      au[1] = *reinterpret_cast<const uint4*>(hb + a_base1 + k0 + a_off);
    };
    auto A_WR2 = [&](int bsel, uint4 (&au)[2]) {
      char* as_ = (char*)&As[bsel][0];
      *reinterpret_cast<uint4*>(as_ + tid*16) = au[0];
      *reinterpret_cast<uint4*>(as_ + 4096 + tid*16) = au[1];
    };

    f32x4 acc[2][4];
    f32x4 z = {0.f, 0.f, 0.f, 0.f};
    #pragma unroll
    for (int m = 0; m < 2; m++)
      #pragma unroll
      for (int n = 0; n < 4; n++) acc[m][n] = z;

    auto COMPUTE = [&](int bsel) {
      const char* asC = (const char*)&As[bsel][0];
      const char* bsC = (const char*)&Bs[bsel][0];
      bf16x8 af[2][2], bq[4][2];
      #pragma unroll
      for (int m = 0; m < 2; m++) {
        int ra = wm*32 + m*16 + l15;
        #pragma unroll
        for (int kk = 0; kk < 2; kk++)
          af[m][kk] = *reinterpret_cast<const bf16x8*>(
              asC + ra*128 + (((kk*4 + l4) ^ (ra & 7)) << 4));
      }
      #pragma unroll
      for (int n = 0; n < 4; n++) {
        int rb = wn*64 + n*16 + l15;
        int Sb = (rb & 7) ^ ((rb >> 3) & 7);
        #pragma unroll
        for (int kk = 0; kk < 2; kk++)
          bq[n][kk] = *reinterpret_cast<const bf16x8*>(
              bsC + rb*128 + (((kk*4 + l4) ^ Sb) << 4));
      }
      #pragma unroll
      for (int kk = 0; kk < 2; kk++)
        #pragma unroll
        for (int m = 0; m < 2; m++)
          #pragma unroll
          for (int n = 0; n < 4; n++)
            acc[m][n] = __builtin_amdgcn_mfma_f32_16x16x32_bf16(af[m][kk], bq[n][kk], acc[m][n], 0, 0, 0);
    };

    // prologue: load slots 0 (k0) and 1 (k1); write buf0 <- slot0
    if (MODE == 1) A_LD1(av0, 0); else A_LD2(au0, 0);
    B_LD(bv0_, 0);
    if (MODE == 1) A_LD1(av1, 64); else A_LD2(au1, 64);
    B_LD(bv1_, 64);
    if (MODE == 1) A_WR1(0, av0); else A_WR2(0, au0);
    B_WR(0, bv0_);
    __syncthreads();

    int cur = 0;
    #pragma unroll
    for (int t = 0; t < NS; t += 2) {
      // even step t: slot0 reloads k(t+2); write buf[cur^1] <- slot1 (k(t+1))
      if (t + 2 < NS) {
        if (MODE == 1) A_LD1(av0, (t+2)*64); else A_LD2(au0, (t+2)*64);
        B_LD(bv0_, (t+2)*64);
      }
      COMPUTE(cur);
      if (t + 1 < NS) {
        if (MODE == 1) A_WR1(cur ^ 1, av1); else A_WR2(cur ^ 1, au1);
        B_WR(cur ^ 1, bv1_);
      }
      __syncthreads();
      cur ^= 1;
      // odd step t+1: slot1 reloads k(t+3); write buf[cur^1] <- slot0 (k(t+2))
      if (t + 3 < NS) {
        if (MODE == 1) A_LD1(av1, (t+3)*64); else A_LD2(au1, (t+3)*64);
        B_LD(bv1_, (t+3)*64);
      }
      COMPUTE(cur);
      if (t + 2 < NS) {
        if (MODE == 1) A_WR1(cur ^ 1, av0); else A_WR2(cur ^ 1, au0);
        B_WR(cur ^ 1, bv0_);
      }
      __syncthreads();
      cur ^= 1;
    }

    if (MODE == 1) {
      #pragma unroll
      for (int m = 0; m < 2; m++)
        #pragma unroll
        for (int j = 0; j < 4; j++) {
          int r = r0 + wm*32 + m*16 + l4*4 + j;
          float wg = wgt_slot[r];
          #pragma unroll
          for (int n = 0; n < 4; n++) {
            int col = nch*128 + wn*64 + n*16 + l15;
            float v = fmaxf(acc[m][n][j], 0.f);
            outp[(size_t)r*EW + col] = __float2bfloat16(v*v*wg);
          }
        }
    } else {
      #pragma unroll
      for (int m = 0; m < 2; m++)
        #pragma unroll
        for (int j = 0; j < 4; j++) {
          int r = r0 + wm*32 + m*16 + l4*4 + j;
          #pragma unroll
          for (int n = 0; n < 4; n++) {
            int col = nch*128 + wn*64 + n*16 + l15;
            outp[(size_t)r*D_EMBD + col] = __float2bfloat16(acc[m][n][j]);
          }
        }
    }
  }
}

// ---------------- combine 8 expert rows per token (vectorized gather) ----------------
__global__ void k_combine(const __hip_bfloat16* __restrict__ y, const int* __restrict__ slot_tk,
                          float* __restrict__ out) {
  __shared__ int s[TOPK];
  int t = blockIdx.x, tid = threadIdx.x;
  if (tid < TOPK) s[tid] = slot_tk[t*TOPK + tid];
  __syncthreads();
  if (tid < 192) {
    int c = tid*4;
    float a0 = 0.f, a1 = 0.f, a2 = 0.f, a3 = 0.f;
    #pragma unroll
    for (int k = 0; k < TOPK; k++) {
      ushort4 v = *reinterpret_cast<const ushort4*>(&y[(size_t)s[k]*D_EMBD + c]);
      union { unsigned int u; float f; } f0, f1, f2, f3;
      f0.u = ((unsigned int)v.x) << 16;
      f1.u = ((unsigned int)v.y) << 16;
      f2.u = ((unsigned int)v.z) << 16;
      f3.u = ((unsigned int)v.w) << 16;
      a0 += f0.f; a1 += f1.f; a2 += f2.f; a3 += f3.f;
    }
    float4 o = {a0, a1, a2, a3};
    *reinterpret_cast<float4*>(&out[(size_t)t*D_EMBD + c]) = o;
  }
}

// ---------------- aux losses + f_i ----------------
__global__ void k_finalize(const int* __restrict__ counts, const float* __restrict__ psum,
                           const float* __restrict__ scal, float* __restrict__ out) {
  __shared__ float part[N_EXP], ptot[N_EXP];
  int e = threadIdx.x;
  float f = (float)counts[e] / 16384.f;
  float p = psum[e] / 2048.f;
  part[e] = f * p;
  ptot[e] = p;
  out[OUT_BASE + 3 + e] = f;
  __syncthreads();
  if (e == 0) {
    float s = 0.f, q = 0.f;
    for (int i = 0; i < N_EXP; i++) { s += part[i]; q += ptot[i]; }
    out[OUT_BASE + 0] = scal[0] / 2048.f;      // router_z_loss
    out[OUT_BASE + 1] = 64.f * s;              // load_balance_loss
    out[OUT_BASE + 2] = q;                     // compute_loss
  }
}

extern "C" void kernel_launch(void* const* d_in, const int* in_sizes, int n_in,
                              void* d_out, int out_size, void* d_ws, size_t ws_size,
                              hipStream_t stream) {
  const float* x  = (const float*)d_in[0];
  const float* rw = (const float*)d_in[1];
  const float* w1 = (const float*)d_in[2];
  const float* w2 = (const float*)d_in[3];
  float* out = (float*)d_out;
  char* ws = (char*)d_ws;

  size_t o = 0;
  auto alloc = [&](size_t b) { size_t r = o; o += (b + 255) & ~(size_t)255; return r; };
  __hip_bfloat16* hprm  = (__hip_bfloat16*)(ws + alloc((size_t)PAD_SLOTS*256*2));
  __hip_bfloat16* yprm  = (__hip_bfloat16*)(ws + alloc((size_t)PAD_SLOTS*768*2));
  float* lp      = (float*)(ws + alloc(3UL*2048*64*4));
  int*   sel_e   = (int*)  (ws + alloc(16384UL*4));
  float* sel_w   = (float*)(ws + alloc(16384UL*4));
  int*   slot_tk = (int*)  (ws + alloc(16384UL*4));
  int*   tokslot = (int*)  (ws + alloc((size_t)PAD_SLOTS*4));
  float* wgtslot = (float*)(ws + alloc((size_t)PAD_SLOTS*4));
  int*   counts  = (int*)  (ws + alloc(256));
  int*   cursor  = (int*)  (ws + alloc(256));
  float* psum    = (float*)(ws + alloc(256));
  float* scal    = (float*)(ws + alloc(256));
  int*   offsets = (int*)  (ws + alloc(256));
  int*   sch_e   = (int*)  (ws + alloc(SCHED_MAX*4));
  int*   sch_r0  = (int*)  (ws + alloc(SCHED_MAX*4));

  k_init<<<80, 256, 0, stream>>>(counts, cursor, psum, scal, wgtslot, tokslot, sch_e);
  k_logits<<<dim3(8, 8, 3), 256, 0, stream>>>(x, rw, lp);
  k_router2<<<256, 256, 0, stream>>>(lp, sel_e, sel_w, counts, psum, scal);
  k_schedule<<<1, 64, 0, stream>>>(counts, offsets, sch_e, sch_r0);
  k_assign<<<64, 256, 0, stream>>>(sel_e, sel_w, offsets, cursor, tokslot, wgtslot, slot_tk);
  k_moe_gemm<1><<<dim3(512, 2), 256, 0, stream>>>((const void*)x, w1, sch_e, sch_r0, tokslot, wgtslot, hprm);
  k_moe_gemm<2><<<dim3(512, 6), 256, 0, stream>>>((const void*)hprm, w2, sch_e, sch_r0, tokslot, wgtslot, yprm);
  k_combine<<<2048, 256, 0, stream>>>(yprm, slot_tk, out);
  k_finalize<<<1, 64, 0, stream>>>(counts, psum, scal, out);
}

// Round 14
// 147.967 us; speedup vs baseline: 1.0115x; 1.0115x over previous
//
#include <hip/hip_runtime.h>
#include <hip/hip_bf16.h>

#define T_TOKENS 2048
#define D_EMBD 768
#define N_EXP 64
#define EW 256
#define TOPK 8
#define TW (N_EXP*EW)
#define PAD_SLOTS 20480   // 16384 + 64*63 rounded up to 64-tile granularity
#define SCHED_MAX 2560    // 8 groups x 320 positions
#define GRP_POS 320
#define OUT_BASE (2048*768)

typedef __attribute__((ext_vector_type(8))) short bf16x8;
typedef __attribute__((ext_vector_type(4))) float f32x4;

__device__ inline unsigned short f2bu(float f) {
  union { __hip_bfloat16 b; unsigned short u; } cv; cv.b = __float2bfloat16(f); return cv.u;
}
__device__ inline unsigned int pk2(float a, float b) {
  return (unsigned int)f2bu(a) | ((unsigned int)f2bu(b) << 16);
}

// ---------------- init ----------------
__global__ void k_init(int* counts, int* cursor, float* psum, float* scal,
                       float* wgt_slot, int* tok_slot, int* sched_e) {
  int i = blockIdx.x*256 + threadIdx.x;   // 20480 threads
  if (i < N_EXP) { counts[i] = 0; cursor[i] = 0; psum[i] = 0.f; }
  if (i < 2) scal[i] = 0.f;
  if (i < PAD_SLOTS) { wgt_slot[i] = 0.f; tok_slot[i] = 0; }
  if (i < SCHED_MAX) sched_e[i] = -1;
}

// ---------------- router logits GEMM: lp[kc][t][e] partial sums ----------------
__global__ __launch_bounds__(256) void k_logits(const float* __restrict__ x,
                                                const float* __restrict__ rw,
                                                float* __restrict__ lp) {
  __shared__ float rw_s[8][256];
  int tid = threadIdx.x;
  int tg = blockIdx.x, eg = blockIdx.y, kc = blockIdx.z;
  #pragma unroll
  for (int idx = 0; idx < 8; idx++)
    rw_s[idx][tid] = rw[(size_t)(eg*8 + idx)*D_EMBD + kc*256 + tid];
  __syncthreads();
  int tok = tg*256 + tid;
  const float4* x4 = reinterpret_cast<const float4*>(x + (size_t)tok*D_EMBD + kc*256);
  float acc[8];
  #pragma unroll
  for (int e = 0; e < 8; e++) acc[e] = 0.f;
  #pragma unroll 4
  for (int k4 = 0; k4 < 64; k4++) {
    float4 xv = x4[k4];
    #pragma unroll
    for (int e = 0; e < 8; e++)
      acc[e] += xv.x*rw_s[e][k4*4+0] + xv.y*rw_s[e][k4*4+1]
              + xv.z*rw_s[e][k4*4+2] + xv.w*rw_s[e][k4*4+3];
  }
  float* dst = lp + (size_t)kc*T_TOKENS*N_EXP + (size_t)tok*N_EXP + eg*8;
  float4 o0 = {acc[0], acc[1], acc[2], acc[3]};
  float4 o1 = {acc[4], acc[5], acc[6], acc[7]};
  reinterpret_cast<float4*>(dst)[0] = o0;
  reinterpret_cast<float4*>(dst)[1] = o1;
}

// ---------------- router part 2: sigmoid, parallel-rank top-8, losses ----------------
__global__ __launch_bounds__(256) void k_router2(const float* __restrict__ lp,
                          int* __restrict__ sel_e, float* __restrict__ sel_w,
                          int* __restrict__ counts, float* __restrict__ psum,
                          float* __restrict__ scal) {
  __shared__ float psum_s[4][64];
  __shared__ int cnt_s[4][64];
  int tid = threadIdx.x, wv = tid >> 6, lane = tid & 63;
  float pacc = 0.f, zacc = 0.f;
  int cacc = 0;
  int tbase = blockIdx.x*8 + wv*2;
  #pragma unroll
  for (int it = 0; it < 2; it++) {
    int t = tbase + it;
    float logit = lp[(size_t)t*N_EXP + lane]
                + lp[(size_t)T_TOKENS*N_EXP + (size_t)t*N_EXP + lane]
                + lp[2*(size_t)T_TOKENS*N_EXP + (size_t)t*N_EXP + lane];
    float prob = 1.f/(1.f + expf(-logit));
    pacc += prob;
    float mx = logit;
    for (int s = 32; s; s >>= 1) mx = fmaxf(mx, __shfl_xor(mx, s, 64));
    float sse = expf(logit - mx);
    for (int s = 32; s; s >>= 1) sse += __shfl_xor(sse, s, 64);
    float lse = mx + logf(sse);
    zacc += lse*lse;
    int rank = 0;
    #pragma unroll
    for (int j = 0; j < 64; j++) {
      float pj = __shfl(prob, j, 64);
      rank += (pj > prob || (pj == prob && j < lane)) ? 1 : 0;
    }
    bool sel = rank < TOPK;
    float sp = sel ? prob : 0.f;
    for (int s = 32; s; s >>= 1) sp += __shfl_xor(sp, s, 64);
    if (sel) {
      sel_e[t*TOPK + rank] = lane;
      sel_w[t*TOPK + rank] = prob / (sp + 1e-20f);
      cacc++;
    }
  }
  psum_s[wv][lane] = pacc;
  cnt_s[wv][lane] = cacc;
  if (lane == 0) atomicAdd(&scal[0], zacc);
  __syncthreads();
  if (tid < 64) {
    float p = psum_s[0][tid] + psum_s[1][tid] + psum_s[2][tid] + psum_s[3][tid];
    int c = cnt_s[0][tid] + cnt_s[1][tid] + cnt_s[2][tid] + cnt_s[3][tid];
    atomicAdd(&psum[tid], p);
    atomicAdd(&counts[tid], c);
  }
}

// ---------------- schedule: 64-row tiles, CONSECUTIVE-expert XCD bands ----------------
// group g = e>>3 owns positions [g*320, g*320+320); within-group rank via segmented scan.
// Experts 8g..8g+7 have ADJACENT weight columns/rows -> each XCD reads a contiguous band.
__global__ void k_schedule(const int* __restrict__ counts, int* __restrict__ offsets,
                           int* __restrict__ sched_e, int* __restrict__ sched_r0) {
  int e = threadIdx.x;   // 64 threads, one wave
  int c = counts[e];
  int tiles = (c + 63) >> 6;
  int padded = tiles << 6;
  int ip = padded;
  for (int s = 1; s < 64; s <<= 1) { int v = __shfl_up(ip, s, 64); if (e >= s) ip += v; }
  int rowoff = ip - padded;
  offsets[e] = rowoff;
  // segmented inclusive scan of tile counts within 8-expert groups
  int it = tiles;
  for (int s = 1; s < 8; s <<= 1) { int v = __shfl_up(it, s, 64); if ((e & 7) >= s) it += v; }
  int rank = it - tiles;
  int grp = e >> 3;
  for (int i = 0; i < tiles; i++) {
    int p = grp*GRP_POS + rank + i;
    sched_e[p] = e;
    sched_r0[p] = rowoff + i*64;
  }
}

// ---------------- assign tokens to slots ----------------
__global__ void k_assign(const int* __restrict__ sel_e, const float* __restrict__ sel_w,
                         const int* __restrict__ offsets, int* __restrict__ cursor,
                         int* __restrict__ tok_slot, float* __restrict__ wgt_slot,
                         int* __restrict__ slot_tk) {
  int i = blockIdx.x*256 + threadIdx.x;   // 16384
  int e = sel_e[i];
  int pos = atomicAdd(&cursor[e], 1);
  int slot = offsets[e] + pos;
  tok_slot[slot] = i >> 3;
  wgt_slot[slot] = sel_w[i];
  slot_tk[i] = slot;
}

// ---------------- grouped GEMM with fused fp32->bf16 convert+transpose staging ----------------
// 64x128 tile, BK=64, double-buffered (round-12 structure).
// Block bid serves ONLY positions of XCD band (bid&7): all 8 same-band experts have
// adjacent weight columns -> dense per-XCD HBM row coverage.
template<int MODE>
__global__ __launch_bounds__(256) void k_moe_gemm(
    const void* __restrict__ Asrc, const float* __restrict__ Bsrc,
    const int* __restrict__ sched_e, const int* __restrict__ sched_r0,
    const int* __restrict__ tok_slot, const float* __restrict__ wgt_slot,
    __hip_bfloat16* __restrict__ outp) {
  constexpr int NS   = (MODE == 1) ? 12 : 4;       // K-steps of 64
  constexpr int BSTR = (MODE == 1) ? TW : D_EMBD;  // native B row stride (fp32)
  __shared__ __hip_bfloat16 As[2][64*64];
  __shared__ __hip_bfloat16 Bs[2][128*64];
  int tid = threadIdx.x;
  int nch = blockIdx.y;
  int n4 = tid & 31, kpb = tid >> 5;     // B staging: col-quad, k-octet
  int mrow = tid >> 4, k4f = tid & 15;   // A staging (MODE1)
  int arl = tid >> 3, akc = tid & 7;     // A staging (MODE2)
  int a_off = ((akc ^ (arl & 7)) << 3);
  int wv = tid >> 6, lane = tid & 63;
  int wm = wv >> 1, wn = wv & 1;
  int l15 = lane & 15, l4 = lane >> 4;

  int xcd = blockIdx.x & 7;
  int q0 = blockIdx.x >> 3;              // 0..63 (gridDim.x = 512)
  for (int q = q0; q < GRP_POS; q += 64) {
    int p = xcd*GRP_POS + q;
    int e = sched_e[p];
    if (e < 0) continue;
    int r0 = sched_r0[p];

    int browb = (MODE == 1) ? 0 : e*EW;                    // B k-row base
    int bcolb = (MODE == 1) ? (e*EW + nch*128) : nch*128;  // B col base

    int tks[4];
    size_t a_base0 = 0, a_base1 = 0;
    if (MODE == 1) {
      #pragma unroll
      for (int i = 0; i < 4; i++) tks[i] = tok_slot[r0 + i*16 + mrow];
    } else {
      a_base0 = (size_t)(r0 + arl) * EW;
      a_base1 = (size_t)(r0 + arl + 32) * EW;
    }

    float bv[8][4], av[4][4];

    auto B_LOAD = [&](int k0) {
      const float* rp = Bsrc + (size_t)(browb + k0 + kpb*8)*BSTR + bcolb + n4*4;
      #pragma unroll
      for (int r = 0; r < 8; r++)
        *reinterpret_cast<float4*>(&bv[r][0]) =
            *reinterpret_cast<const float4*>(rp + (size_t)r*BSTR);
    };
    auto B_WRITE = [&](int bsel) {
      char* bs = (char*)&Bs[bsel][0];
      #pragma unroll
      for (int c = 0; c < 4; c++) {
        int n = n4*4 + c;
        int ch = kpb ^ ((n & 7) ^ ((n >> 3) & 7));
        uint4 o = { pk2(bv[0][c], bv[1][c]), pk2(bv[2][c], bv[3][c]),
                    pk2(bv[4][c], bv[5][c]), pk2(bv[6][c], bv[7][c]) };
        *reinterpret_cast<uint4*>(bs + n*128 + ch*16) = o;
      }
    };
    auto A_LOAD1 = [&](int k0) {
      const float* xf = (const float*)Asrc;
      #pragma unroll
      for (int i = 0; i < 4; i++)
        *reinterpret_cast<float4*>(&av[i][0]) =
            *reinterpret_cast<const float4*>(xf + (size_t)tks[i]*D_EMBD + k0 + k4f*4);
    };
    auto A_WRITE1 = [&](int bsel) {
      char* as_ = (char*)&As[bsel][0];
      #pragma unroll
      for (int i = 0; i < 4; i++) {
        int m = i*16 + mrow;
        int ch = (k4f >> 1) ^ (m & 7);
        uint2 val = { pk2(av[i][0], av[i][1]), pk2(av[i][2], av[i][3]) };
        *reinterpret_cast<uint2*>(as_ + m*128 + ch*16 + (k4f & 1)*8) = val;
      }
    };
    auto A_LOAD2 = [&](int k0) {
      const __hip_bfloat16* hb = (const __hip_bfloat16*)Asrc;
      *reinterpret_cast<uint4*>(&av[0][0]) =
          *reinterpret_cast<const uint4*>(hb + a_base0 + k0 + a_off);
      *reinterpret_cast<uint4*>(&av[2][0]) =
          *reinterpret_cast<const uint4*>(hb + a_base1 + k0 + a_off);
    };
    auto A_WRITE2 = [&](int bsel) {
      char* as_ = (char*)&As[bsel][0];
      *reinterpret_cast<uint4*>(as_ + tid*16) = *reinterpret_cast<uint4*>(&av[0][0]);
      *reinterpret_cast<uint4*>(as_ + 4096 + tid*16) = *reinterpret_cast<uint4*>(&av[2][0]);
    };

    f32x4 acc[2][4];
    f32x4 z = {0.f, 0.f, 0.f, 0.f};
    #pragma unroll
    for (int m = 0; m < 2; m++)
      #pragma unroll
      for (int n = 0; n < 4; n++) acc[m][n] = z;

    // prologue: stage step 0 into buf 0
    if (MODE == 1) { A_LOAD1(0); B_LOAD(0); A_WRITE1(0); B_WRITE(0); }
    else           { A_LOAD2(0); B_LOAD(0); A_WRITE2(0); B_WRITE(0); }
    __syncthreads();

    int cur = 0;
    for (int step = 0; step < NS; step++) {
      bool more = (step + 1 < NS);
      int k1 = (step + 1)*64;
      if (more) {
        if (MODE == 1) { A_LOAD1(k1); B_LOAD(k1); }
        else           { A_LOAD2(k1); B_LOAD(k1); }
      }
      const char* asC = (const char*)&As[cur][0];
      const char* bsC = (const char*)&Bs[cur][0];
      bf16x8 af[2][2], bq[4][2];
      #pragma unroll
      for (int m = 0; m < 2; m++) {
        int ra = wm*32 + m*16 + l15;
        #pragma unroll
        for (int kk = 0; kk < 2; kk++)
          af[m][kk] = *reinterpret_cast<const bf16x8*>(
              asC + ra*128 + (((kk*4 + l4) ^ (ra & 7)) << 4));
      }
      #pragma unroll
      for (int n = 0; n < 4; n++) {
        int rb = wn*64 + n*16 + l15;
        int Sb = (rb & 7) ^ ((rb >> 3) & 7);
        #pragma unroll
        for (int kk = 0; kk < 2; kk++)
          bq[n][kk] = *reinterpret_cast<const bf16x8*>(
              bsC + rb*128 + (((kk*4 + l4) ^ Sb) << 4));
      }
      #pragma unroll
      for (int kk = 0; kk < 2; kk++)
        #pragma unroll
        for (int m = 0; m < 2; m++)
          #pragma unroll
          for (int n = 0; n < 4; n++)
            acc[m][n] = __builtin_amdgcn_mfma_f32_16x16x32_bf16(af[m][kk], bq[n][kk], acc[m][n], 0, 0, 0);
      if (more) {
        if (MODE == 1) { A_WRITE1(cur ^ 1); B_WRITE(cur ^ 1); }
        else           { A_WRITE2(cur ^ 1); B_WRITE(cur ^ 1); }
      }
      __syncthreads();
      cur ^= 1;
    }

    if (MODE == 1) {
      #pragma unroll
      for (int m = 0; m < 2; m++)
        #pragma unroll
        for (int j = 0; j < 4; j++) {
          int r = r0 + wm*32 + m*16 + l4*4 + j;
          float wg = wgt_slot[r];
          #pragma unroll
          for (int n = 0; n < 4; n++) {
            int col = nch*128 + wn*64 + n*16 + l15;
            float v = fmaxf(acc[m][n][j], 0.f);
            outp[(size_t)r*EW + col] = __float2bfloat16(v*v*wg);
          }
        }
    } else {
      #pragma unroll
      for (int m = 0; m < 2; m++)
        #pragma unroll
        for (int j = 0; j < 4; j++) {
          int r = r0 + wm*32 + m*16 + l4*4 + j;
          #pragma unroll
          for (int n = 0; n < 4; n++) {
            int col = nch*128 + wn*64 + n*16 + l15;
            outp[(size_t)r*D_EMBD + col] = __float2bfloat16(acc[m][n][j]);
          }
        }
    }
  }
}

// ---------------- combine 8 expert rows per token (vectorized gather) ----------------
__global__ void k_combine(const __hip_bfloat16* __restrict__ y, const int* __restrict__ slot_tk,
                          float* __restrict__ out) {
  __shared__ int s[TOPK];
  int t = blockIdx.x, tid = threadIdx.x;
  if (tid < TOPK) s[tid] = slot_tk[t*TOPK + tid];
  __syncthreads();
  if (tid < 192) {
    int c = tid*4;
    float a0 = 0.f, a1 = 0.f, a2 = 0.f, a3 = 0.f;
    #pragma unroll
    for (int k = 0; k < TOPK; k++) {
      ushort4 v = *reinterpret_cast<const ushort4*>(&y[(size_t)s[k]*D_EMBD + c]);
      union { unsigned int u; float f; } f0, f1, f2, f3;
      f0.u = ((unsigned int)v.x) << 16;
      f1.u = ((unsigned int)v.y) << 16;
      f2.u = ((unsigned int)v.z) << 16;
      f3.u = ((unsigned int)v.w) << 16;
      a0 += f0.f; a1 += f1.f; a2 += f2.f; a3 += f3.f;
    }
    float4 o = {a0, a1, a2, a3};
    *reinterpret_cast<float4*>(&out[(size_t)t*D_EMBD + c]) = o;
  }
}

// ---------------- aux losses + f_i ----------------
__global__ void k_finalize(const int* __restrict__ counts, const float* __restrict__ psum,
                           const float* __restrict__ scal, float* __restrict__ out) {
  __shared__ float part[N_EXP], ptot[N_EXP];
  int e = threadIdx.x;
  float f = (float)counts[e] / 16384.f;
  float p = psum[e] / 2048.f;
  part[e] = f * p;
  ptot[e] = p;
  out[OUT_BASE + 3 + e] = f;
  __syncthreads();
  if (e == 0) {
    float s = 0.f, q = 0.f;
    for (int i = 0; i < N_EXP; i++) { s += part[i]; q += ptot[i]; }
    out[OUT_BASE + 0] = scal[0] / 2048.f;      // router_z_loss
    out[OUT_BASE + 1] = 64.f * s;              // load_balance_loss
    out[OUT_BASE + 2] = q;                     // compute_loss
  }
}

extern "C" void kernel_launch(void* const* d_in, const int* in_sizes, int n_in,
                              void* d_out, int out_size, void* d_ws, size_t ws_size,
                              hipStream_t stream) {
  const float* x  = (const float*)d_in[0];
  const float* rw = (const float*)d_in[1];
  const float* w1 = (const float*)d_in[2];
  const float* w2 = (const float*)d_in[3];
  float* out = (float*)d_out;
  char* ws = (char*)d_ws;

  size_t o = 0;
  auto alloc = [&](size_t b) { size_t r = o; o += (b + 255) & ~(size_t)255; return r; };
  __hip_bfloat16* hprm  = (__hip_bfloat16*)(ws + alloc((size_t)PAD_SLOTS*256*2));
  __hip_bfloat16* yprm  = (__hip_bfloat16*)(ws + alloc((size_t)PAD_SLOTS*768*2));
  float* lp      = (float*)(ws + alloc(3UL*2048*64*4));
  int*   sel_e   = (int*)  (ws + alloc(16384UL*4));
  float* sel_w   = (float*)(ws + alloc(16384UL*4));
  int*   slot_tk = (int*)  (ws + alloc(16384UL*4));
  int*   tokslot = (int*)  (ws + alloc((size_t)PAD_SLOTS*4));
  float* wgtslot = (float*)(ws + alloc((size_t)PAD_SLOTS*4));
  int*   counts  = (int*)  (ws + alloc(256));
  int*   cursor  = (int*)  (ws + alloc(256));
  float* psum    = (float*)(ws + alloc(256));
  float* scal    = (float*)(ws + alloc(256));
  int*   offsets = (int*)  (ws + alloc(256));
  int*   sch_e   = (int*)  (ws + alloc(SCHED_MAX*4));
  int*   sch_r0  = (int*)  (ws + alloc(SCHED_MAX*4));

  k_init<<<80, 256, 0, stream>>>(counts, cursor, psum, scal, wgtslot, tokslot, sch_e);
  k_logits<<<dim3(8, 8, 3), 256, 0, stream>>>(x, rw, lp);
  k_router2<<<256, 256, 0, stream>>>(lp, sel_e, sel_w, counts, psum, scal);
  k_schedule<<<1, 64, 0, stream>>>(counts, offsets, sch_e, sch_r0);
  k_assign<<<64, 256, 0, stream>>>(sel_e, sel_w, offsets, cursor, tokslot, wgtslot, slot_tk);
  k_moe_gemm<1><<<dim3(512, 2), 256, 0, stream>>>((const void*)x, w1, sch_e, sch_r0, tokslot, wgtslot, hprm);
  k_moe_gemm<2><<<dim3(512, 6), 256, 0, stream>>>((const void*)hprm, w2, sch_e, sch_r0, tokslot, wgtslot, yprm);
  k_combine<<<2048, 256, 0, stream>>>(yprm, slot_tk, out);
  k_finalize<<<1, 64, 0, stream>>>(counts, psum, scal, out);
}

// Round 15
// 144.977 us; speedup vs baseline: 1.0324x; 1.0206x over previous
//
#include <hip/hip_runtime.h>
#include <hip/hip_bf16.h>

#define T_TOKENS 2048
#define D_EMBD 768
#define N_EXP 64
#define EW 256
#define TOPK 8
#define TW (N_EXP*EW)
#define PAD_SLOTS 32768   // 16384 + 64*255 worst-case 256-row padding
#define SCHED_MAX 128     // sum ceil(count/256) <= 128
#define OUT_BASE (2048*768)

typedef __attribute__((ext_vector_type(8))) short bf16x8;
typedef __attribute__((ext_vector_type(4))) float f32x4;

typedef __attribute__((address_space(1))) void GAS;
typedef __attribute__((address_space(3))) void LAS;
#define GLOAD16(g, l) __builtin_amdgcn_global_load_lds((GAS*)(g), (LAS*)(l), 16, 0, 0)

__device__ inline unsigned short f2bu(float f) {
  union { __hip_bfloat16 b; unsigned short u; } cv; cv.b = __float2bfloat16(f); return cv.u;
}
__device__ inline unsigned int pk2(float a, float b) {
  return (unsigned int)f2bu(a) | ((unsigned int)f2bu(b) << 16);
}

// ---------------- init ----------------
__global__ void k_init(int* counts, int* cursor, float* psum, float* scal,
                       float* wgt_slot, int* tok_slot, int* sched_e) {
  int i = blockIdx.x*256 + threadIdx.x;   // 32768 threads
  if (i < N_EXP) { counts[i] = 0; cursor[i] = 0; psum[i] = 0.f; }
  if (i < 2) scal[i] = 0.f;
  if (i < PAD_SLOTS) { wgt_slot[i] = 0.f; tok_slot[i] = 0; }
  if (i < SCHED_MAX) sched_e[i] = -1;
}

// ---------------- x -> bf16 ----------------
__global__ void k_cvt_x(const float* __restrict__ x, __hip_bfloat16* __restrict__ xb) {
  int i = blockIdx.x*256 + threadIdx.x;   // 393216 float4
  float4 v = reinterpret_cast<const float4*>(x)[i];
  ushort4 o;
  o.x = f2bu(v.x); o.y = f2bu(v.y); o.z = f2bu(v.z); o.w = f2bu(v.w);
  reinterpret_cast<ushort4*>(xb)[i] = o;
}

// ---------------- router logits GEMM: lp[kc][t][e] partial sums ----------------
__global__ __launch_bounds__(256) void k_logits(const float* __restrict__ x,
                                                const float* __restrict__ rw,
                                                float* __restrict__ lp) {
  __shared__ float rw_s[8][256];
  int tid = threadIdx.x;
  int tg = blockIdx.x, eg = blockIdx.y, kc = blockIdx.z;
  #pragma unroll
  for (int idx = 0; idx < 8; idx++)
    rw_s[idx][tid] = rw[(size_t)(eg*8 + idx)*D_EMBD + kc*256 + tid];
  __syncthreads();
  int tok = tg*256 + tid;
  const float4* x4 = reinterpret_cast<const float4*>(x + (size_t)tok*D_EMBD + kc*256);
  float acc[8];
  #pragma unroll
  for (int e = 0; e < 8; e++) acc[e] = 0.f;
  #pragma unroll 4
  for (int k4 = 0; k4 < 64; k4++) {
    float4 xv = x4[k4];
    #pragma unroll
    for (int e = 0; e < 8; e++)
      acc[e] += xv.x*rw_s[e][k4*4+0] + xv.y*rw_s[e][k4*4+1]
              + xv.z*rw_s[e][k4*4+2] + xv.w*rw_s[e][k4*4+3];
  }
  float* dst = lp + (size_t)kc*T_TOKENS*N_EXP + (size_t)tok*N_EXP + eg*8;
  float4 o0 = {acc[0], acc[1], acc[2], acc[3]};
  float4 o1 = {acc[4], acc[5], acc[6], acc[7]};
  reinterpret_cast<float4*>(dst)[0] = o0;
  reinterpret_cast<float4*>(dst)[1] = o1;
}

// ---------------- router part 2: sigmoid, parallel-rank top-8, losses ----------------
__global__ __launch_bounds__(256) void k_router2(const float* __restrict__ lp,
                          int* __restrict__ sel_e, float* __restrict__ sel_w,
                          int* __restrict__ counts, float* __restrict__ psum,
                          float* __restrict__ scal) {
  __shared__ float psum_s[4][64];
  __shared__ int cnt_s[4][64];
  int tid = threadIdx.x, wv = tid >> 6, lane = tid & 63;
  float pacc = 0.f, zacc = 0.f;
  int cacc = 0;
  int tbase = blockIdx.x*8 + wv*2;
  #pragma unroll
  for (int it = 0; it < 2; it++) {
    int t = tbase + it;
    float logit = lp[(size_t)t*N_EXP + lane]
                + lp[(size_t)T_TOKENS*N_EXP + (size_t)t*N_EXP + lane]
                + lp[2*(size_t)T_TOKENS*N_EXP + (size_t)t*N_EXP + lane];
    float prob = 1.f/(1.f + expf(-logit));
    pacc += prob;
    float mx = logit;
    for (int s = 32; s; s >>= 1) mx = fmaxf(mx, __shfl_xor(mx, s, 64));
    float sse = expf(logit - mx);
    for (int s = 32; s; s >>= 1) sse += __shfl_xor(sse, s, 64);
    float lse = mx + logf(sse);
    zacc += lse*lse;
    int rank = 0;
    #pragma unroll
    for (int j = 0; j < 64; j++) {
      float pj = __shfl(prob, j, 64);
      rank += (pj > prob || (pj == prob && j < lane)) ? 1 : 0;
    }
    bool sel = rank < TOPK;
    float sp = sel ? prob : 0.f;
    for (int s = 32; s; s >>= 1) sp += __shfl_xor(sp, s, 64);
    if (sel) {
      sel_e[t*TOPK + rank] = lane;
      sel_w[t*TOPK + rank] = prob / (sp + 1e-20f);
      cacc++;
    }
  }
  psum_s[wv][lane] = pacc;
  cnt_s[wv][lane] = cacc;
  if (lane == 0) atomicAdd(&scal[0], zacc);
  __syncthreads();
  if (tid < 64) {
    float p = psum_s[0][tid] + psum_s[1][tid] + psum_s[2][tid] + psum_s[3][tid];
    int c = cnt_s[0][tid] + cnt_s[1][tid] + cnt_s[2][tid] + cnt_s[3][tid];
    atomicAdd(&psum[tid], p);
    atomicAdd(&counts[tid], c);
  }
}

// ---------------- schedule: 256-row tiles, linear positions ----------------
__global__ void k_schedule(const int* __restrict__ counts, int* __restrict__ offsets,
                           int* __restrict__ sched_e, int* __restrict__ sched_r0) {
  int e = threadIdx.x;   // 64 threads, one wave
  int c = counts[e];
  int tiles = (c + 255) >> 8;
  int padded = tiles << 8;
  int ip = padded;
  for (int s = 1; s < 64; s <<= 1) { int v = __shfl_up(ip, s, 64); if (e >= s) ip += v; }
  int rowoff = ip - padded;
  offsets[e] = rowoff;
  int it = tiles;
  for (int s = 1; s < 64; s <<= 1) { int v = __shfl_up(it, s, 64); if (e >= s) it += v; }
  int rank = it - tiles;
  for (int i = 0; i < tiles; i++) {
    sched_e[rank + i] = e;
    sched_r0[rank + i] = rowoff + i*256;
  }
}

// ---------------- assign tokens to slots ----------------
__global__ void k_assign(const int* __restrict__ sel_e, const float* __restrict__ sel_w,
                         const int* __restrict__ offsets, int* __restrict__ cursor,
                         int* __restrict__ tok_slot, float* __restrict__ wgt_slot,
                         int* __restrict__ slot_tk) {
  int i = blockIdx.x*256 + threadIdx.x;   // 16384
  int e = sel_e[i];
  int pos = atomicAdd(&cursor[e], 1);
  int slot = offsets[e] + pos;
  tok_slot[slot] = i >> 3;
  wgt_slot[slot] = sel_w[i];
  slot_tk[i] = slot;
}

// ---------------- grouped GEMM: 256x128 tile, BK=64, 512 threads, fused cvt staging ----
// MODE 1: A = xb bf16 (gathered, global_load_lds), B = w1 fp32 native [768][16384]
//         h[slot] = relu(x@W1_e)^2 * gate   (K=768, 12 steps, grid (128,2))
// MODE 2: A = hprm bf16 (global_load_lds),  B = w2 fp32 native [16384][768]
//         y[slot] = h@W2_e                  (K=256, 4 steps, grid (128,6))
// B staging: thread = (col-pair cp, k-octet ko): 8 float2 stride-BSTR loads ->
//   2 uint4 writes at n*128 + (ko^S(n))*16, S(n)=(n&7)^((n>>3)&7)  [2-way, free]
// A staging: 4x GLOAD16, linear LDS dest + source-swizzled chunk (rule #21).
template<int MODE>
__global__ __launch_bounds__(512) void k_moe_gemm(
    const void* __restrict__ Asrc, const float* __restrict__ Bsrc,
    const int* __restrict__ sched_e, const int* __restrict__ sched_r0,
    const int* __restrict__ tok_slot, const float* __restrict__ wgt_slot,
    __hip_bfloat16* __restrict__ outp) {
  constexpr int NS   = (MODE == 1) ? 12 : 4;
  constexpr int BSTR = (MODE == 1) ? TW : D_EMBD;
  __shared__ __hip_bfloat16 As[2][256*64];   // 32 KB each
  __shared__ __hip_bfloat16 Bs[2][128*64];   // 16 KB each
  int tid = threadIdx.x;
  int nch = blockIdx.y;
  int cp = tid & 63, ko = tid >> 6;          // B staging: col-pair, k-octet (0..7)
  int arl = tid >> 3, akc = tid & 7;         // A gload rows/chunks
  int aoff = (akc ^ (arl & 7))*8;            // bf16 elements
  int wv = tid >> 6, lane = tid & 63;
  int wm = wv >> 1, wn = wv & 1;             // 4M x 2N wave grid
  int l15 = lane & 15, l4 = lane >> 4;

  int p = blockIdx.x;
  int e = sched_e[p];
  if (e < 0) return;
  int r0 = sched_r0[p];

  // B source bases
  size_t brow0 = (MODE == 1) ? 0 : (size_t)e*EW;
  int bcol = (MODE == 1) ? (e*EW + nch*128) : nch*128;

  // A source bases (4 rows each 64 apart)
  size_t abase[4];
  #pragma unroll
  for (int i = 0; i < 4; i++) {
    if (MODE == 1) abase[i] = (size_t)tok_slot[r0 + i*64 + arl] * D_EMBD;
    else           abase[i] = (size_t)(r0 + i*64 + arl) * EW;
  }

  float2 bv[8];

  auto B_LD = [&](int k0) {
    const float* rp = Bsrc + (brow0 + k0 + ko*8)*BSTR + bcol + cp*2;
    #pragma unroll
    for (int r = 0; r < 8; r++)
      bv[r] = *reinterpret_cast<const float2*>(rp + (size_t)r*BSTR);
  };
  auto B_WR = [&](int bsel) {
    char* bs = (char*)&Bs[bsel][0];
    #pragma unroll
    for (int c = 0; c < 2; c++) {
      int n = cp*2 + c;
      int ch = ko ^ ((n & 7) ^ ((n >> 3) & 7));
      float v0 = c ? bv[0].y : bv[0].x, v1 = c ? bv[1].y : bv[1].x;
      float v2 = c ? bv[2].y : bv[2].x, v3 = c ? bv[3].y : bv[3].x;
      float v4 = c ? bv[4].y : bv[4].x, v5 = c ? bv[5].y : bv[5].x;
      float v6 = c ? bv[6].y : bv[6].x, v7 = c ? bv[7].y : bv[7].x;
      uint4 o = { pk2(v0, v1), pk2(v2, v3), pk2(v4, v5), pk2(v6, v7) };
      *reinterpret_cast<uint4*>(bs + n*128 + ch*16) = o;
    }
  };
  auto A_ST = [&](int bsel, int k0) {
    const __hip_bfloat16* ab = (const __hip_bfloat16*)Asrc;
    #pragma unroll
    for (int i = 0; i < 4; i++)
      GLOAD16(ab + abase[i] + k0 + aoff, &As[bsel][0] + (i*512 + tid)*8);
  };

  f32x4 acc[4][4];
  f32x4 z = {0.f, 0.f, 0.f, 0.f};
  #pragma unroll
  for (int m = 0; m < 4; m++)
    #pragma unroll
    for (int n = 0; n < 4; n++) acc[m][n] = z;

  auto COMPUTE = [&](int bsel) {
    const char* asC = (const char*)&As[bsel][0];
    const char* bsC = (const char*)&Bs[bsel][0];
    bf16x8 af[4][2], bq[4][2];
    #pragma unroll
    for (int m = 0; m < 4; m++) {
      int ra = wm*64 + m*16 + l15;
      #pragma unroll
      for (int kk = 0; kk < 2; kk++)
        af[m][kk] = *reinterpret_cast<const bf16x8*>(
            asC + ra*128 + (((kk*4 + l4) ^ (ra & 7)) << 4));
    }
    #pragma unroll
    for (int n = 0; n < 4; n++) {
      int rb = wn*64 + n*16 + l15;
      int Sb = (rb & 7) ^ ((rb >> 3) & 7);
      #pragma unroll
      for (int kk = 0; kk < 2; kk++)
        bq[n][kk] = *reinterpret_cast<const bf16x8*>(
            bsC + rb*128 + (((kk*4 + l4) ^ Sb) << 4));
    }
    #pragma unroll
    for (int kk = 0; kk < 2; kk++)
      #pragma unroll
      for (int m = 0; m < 4; m++)
        #pragma unroll
        for (int n = 0; n < 4; n++)
          acc[m][n] = __builtin_amdgcn_mfma_f32_16x16x32_bf16(af[m][kk], bq[n][kk], acc[m][n], 0, 0, 0);
  };

  // prologue
  A_ST(0, 0);
  B_LD(0);
  B_WR(0);
  asm volatile("s_waitcnt vmcnt(0)" ::: "memory");
  __syncthreads();

  int cur = 0;
  for (int step = 0; step < NS; step++) {
    bool more = (step + 1 < NS);
    if (more) { A_ST(cur ^ 1, (step + 1)*64); B_LD((step + 1)*64); }
    COMPUTE(cur);
    if (more) B_WR(cur ^ 1);
    asm volatile("s_waitcnt vmcnt(0)" ::: "memory");
    __syncthreads();
    cur ^= 1;
  }

  if (MODE == 1) {
    #pragma unroll
    for (int m = 0; m < 4; m++)
      #pragma unroll
      for (int j = 0; j < 4; j++) {
        int r = r0 + wm*64 + m*16 + l4*4 + j;
        float wg = wgt_slot[r];
        #pragma unroll
        for (int n = 0; n < 4; n++) {
          int col = nch*128 + wn*64 + n*16 + l15;
          float v = fmaxf(acc[m][n][j], 0.f);
          outp[(size_t)r*EW + col] = __float2bfloat16(v*v*wg);
        }
      }
  } else {
    #pragma unroll
    for (int m = 0; m < 4; m++)
      #pragma unroll
      for (int j = 0; j < 4; j++) {
        int r = r0 + wm*64 + m*16 + l4*4 + j;
        #pragma unroll
        for (int n = 0; n < 4; n++) {
          int col = nch*128 + wn*64 + n*16 + l15;
          outp[(size_t)r*D_EMBD + col] = __float2bfloat16(acc[m][n][j]);
        }
      }
  }
}

// ---------------- combine 8 expert rows per token (vectorized gather) ----------------
__global__ void k_combine(const __hip_bfloat16* __restrict__ y, const int* __restrict__ slot_tk,
                          float* __restrict__ out) {
  __shared__ int s[TOPK];
  int t = blockIdx.x, tid = threadIdx.x;
  if (tid < TOPK) s[tid] = slot_tk[t*TOPK + tid];
  __syncthreads();
  if (tid < 192) {
    int c = tid*4;
    float a0 = 0.f, a1 = 0.f, a2 = 0.f, a3 = 0.f;
    #pragma unroll
    for (int k = 0; k < TOPK; k++) {
      ushort4 v = *reinterpret_cast<const ushort4*>(&y[(size_t)s[k]*D_EMBD + c]);
      union { unsigned int u; float f; } f0, f1, f2, f3;
      f0.u = ((unsigned int)v.x) << 16;
      f1.u = ((unsigned int)v.y) << 16;
      f2.u = ((unsigned int)v.z) << 16;
      f3.u = ((unsigned int)v.w) << 16;
      a0 += f0.f; a1 += f1.f; a2 += f2.f; a3 += f3.f;
    }
    float4 o = {a0, a1, a2, a3};
    *reinterpret_cast<float4*>(&out[(size_t)t*D_EMBD + c]) = o;
  }
}

// ---------------- aux losses + f_i ----------------
__global__ void k_finalize(const int* __restrict__ counts, const float* __restrict__ psum,
                           const float* __restrict__ scal, float* __restrict__ out) {
  __shared__ float part[N_EXP], ptot[N_EXP];
  int e = threadIdx.x;
  float f = (float)counts[e] / 16384.f;
  float p = psum[e] / 2048.f;
  part[e] = f * p;
  ptot[e] = p;
  out[OUT_BASE + 3 + e] = f;
  __syncthreads();
  if (e == 0) {
    float s = 0.f, q = 0.f;
    for (int i = 0; i < N_EXP; i++) { s += part[i]; q += ptot[i]; }
    out[OUT_BASE + 0] = scal[0] / 2048.f;      // router_z_loss
    out[OUT_BASE + 1] = 64.f * s;              // load_balance_loss
    out[OUT_BASE + 2] = q;                     // compute_loss
  }
}

extern "C" void kernel_launch(void* const* d_in, const int* in_sizes, int n_in,
                              void* d_out, int out_size, void* d_ws, size_t ws_size,
                              hipStream_t stream) {
  const float* x  = (const float*)d_in[0];
  const float* rw = (const float*)d_in[1];
  const float* w1 = (const float*)d_in[2];
  const float* w2 = (const float*)d_in[3];
  float* out = (float*)d_out;
  char* ws = (char*)d_ws;

  size_t o = 0;
  auto alloc = [&](size_t b) { size_t r = o; o += (b + 255) & ~(size_t)255; return r; };
  __hip_bfloat16* xb    = (__hip_bfloat16*)(ws + alloc(2048UL*768*2));
  __hip_bfloat16* hprm  = (__hip_bfloat16*)(ws + alloc((size_t)PAD_SLOTS*256*2));
  __hip_bfloat16* yprm  = (__hip_bfloat16*)(ws + alloc((size_t)PAD_SLOTS*768*2));
  float* lp      = (float*)(ws + alloc(3UL*2048*64*4));
  int*   sel_e   = (int*)  (ws + alloc(16384UL*4));
  float* sel_w   = (float*)(ws + alloc(16384UL*4));
  int*   slot_tk = (int*)  (ws + alloc(16384UL*4));
  int*   tokslot = (int*)  (ws + alloc((size_t)PAD_SLOTS*4));
  float* wgtslot = (float*)(ws + alloc((size_t)PAD_SLOTS*4));
  int*   counts  = (int*)  (ws + alloc(256));
  int*   cursor  = (int*)  (ws + alloc(256));
  float* psum    = (float*)(ws + alloc(256));
  float* scal    = (float*)(ws + alloc(256));
  int*   offsets = (int*)  (ws + alloc(256));
  int*   sch_e   = (int*)  (ws + alloc(SCHED_MAX*4));
  int*   sch_r0  = (int*)  (ws + alloc(SCHED_MAX*4));

  k_init<<<128, 256, 0, stream>>>(counts, cursor, psum, scal, wgtslot, tokslot, sch_e);
  k_cvt_x<<<1536, 256, 0, stream>>>(x, xb);
  k_logits<<<dim3(8, 8, 3), 256, 0, stream>>>(x, rw, lp);
  k_router2<<<256, 256, 0, stream>>>(lp, sel_e, sel_w, counts, psum, scal);
  k_schedule<<<1, 64, 0, stream>>>(counts, offsets, sch_e, sch_r0);
  k_assign<<<64, 256, 0, stream>>>(sel_e, sel_w, offsets, cursor, tokslot, wgtslot, slot_tk);
  k_moe_gemm<1><<<dim3(SCHED_MAX, 2), 512, 0, stream>>>((const void*)xb, w1, sch_e, sch_r0, tokslot, wgtslot, hprm);
  k_moe_gemm<2><<<dim3(SCHED_MAX, 6), 512, 0, stream>>>((const void*)hprm, w2, sch_e, sch_r0, tokslot, wgtslot, yprm);
  k_combine<<<2048, 256, 0, stream>>>(yprm, slot_tk, out);
  k_finalize<<<1, 64, 0, stream>>>(counts, psum, scal, out);
}